// Round 4
// baseline (309.681 us; speedup 1.0000x reference)
//
#include <hip/hip_runtime.h>
#include <math.h>

#define Hh 128
#define Ww 128
#define Dd 256
#define Bb 4
#define HW (Hh*Ww)        // 16384
#define NPIX (Bb*HW)      // 65536
#define WP 132            // padded width/height (2-px zero ring)

typedef __attribute__((ext_vector_type(8))) short s16x8;   // 8 bf16 (4 VGPRs)
typedef __attribute__((ext_vector_type(4))) float f32x4;

// ---------- wave (64-lane) butterfly reductions ----------
__device__ __forceinline__ float wsum(float v) {
#pragma unroll
    for (int o = 32; o; o >>= 1) v += __shfl_xor(v, o, 64);
    return v;
}

// fp32 -> bf16 RNE
__device__ __forceinline__ unsigned short f2bf(float f) {
    unsigned u = __float_as_uint(f);
    u += 0x7FFF + ((u >> 16) & 1);
    return (unsigned short)(u >> 16);
}

__device__ __forceinline__ float gelu_exact(float v) {
    return 0.5f * v * (1.0f + erff(v * 0.70710678118654752f));
}

// ---------- K1: L2-normalize vis tokens -> kn [B,H,W,D] bf16 ----------
__global__ __launch_bounds__(256) void norm_vis(const float* __restrict__ vis,
                                                unsigned short* __restrict__ kn) {
    int wid = threadIdx.x >> 6, lane = threadIdx.x & 63;
    int pix = blockIdx.x * 4 + wid;
    const float4 v = *(const float4*)(vis + (size_t)pix * Dd + lane * 4);
    float ss = wsum(v.x * v.x + v.y * v.y + v.z * v.z + v.w * v.w);
    float inv = 1.0f / fmaxf(sqrtf(ss), 1e-12f);
    ushort4 o;
    o.x = f2bf(v.x * inv); o.y = f2bf(v.y * inv);
    o.z = f2bf(v.z * inv); o.w = f2bf(v.w * inv);
    *(ushort4*)(kn + (size_t)pix * Dd + lane * 4) = o;
}

// ---------- K2: bilinear-upsample rubin 64x64 -> 128x128 + L2 norm -> qn bf16 ----------
__global__ __launch_bounds__(256) void interp_norm_q(const float* __restrict__ rub,
                                                     unsigned short* __restrict__ qn) {
    int wid = threadIdx.x >> 6, lane = threadIdx.x & 63;
    int pix = blockIdx.x * 4 + wid;
    int b = pix >> 14; int yx = pix & 16383; int y = yx >> 7; int x = yx & 127;
    float sy = 0.5f * y - 0.25f;
    float sx = 0.5f * x - 0.25f;
    int y0 = (int)floorf(sy); float fy = sy - (float)y0;
    int x0 = (int)floorf(sx); float fx = sx - (float)x0;
    int y0c = max(y0, 0), y1c = min(y0 + 1, 63);
    int x0c = max(x0, 0), x1c = min(x0 + 1, 63);
    const float* base = rub + (size_t)b * 4096 * Dd;
    const float4 v00 = *(const float4*)(base + (size_t)(y0c * 64 + x0c) * Dd + lane * 4);
    const float4 v01 = *(const float4*)(base + (size_t)(y0c * 64 + x1c) * Dd + lane * 4);
    const float4 v10 = *(const float4*)(base + (size_t)(y1c * 64 + x0c) * Dd + lane * 4);
    const float4 v11 = *(const float4*)(base + (size_t)(y1c * 64 + x1c) * Dd + lane * 4);
    float w00 = (1.f - fy) * (1.f - fx), w01 = (1.f - fy) * fx;
    float w10 = fy * (1.f - fx), w11 = fy * fx;
    float4 v;
    v.x = w00 * v00.x + w01 * v01.x + w10 * v10.x + w11 * v11.x;
    v.y = w00 * v00.y + w01 * v01.y + w10 * v10.y + w11 * v11.y;
    v.z = w00 * v00.z + w01 * v01.z + w10 * v10.z + w11 * v11.z;
    v.w = w00 * v00.w + w01 * v01.w + w10 * v10.w + w11 * v11.w;
    float ss = wsum(v.x * v.x + v.y * v.y + v.z * v.z + v.w * v.w);
    float inv = 1.0f / fmaxf(sqrtf(ss), 1e-12f);
    ushort4 o;
    o.x = f2bf(v.x * inv); o.y = f2bf(v.y * inv);
    o.z = f2bf(v.z * inv); o.w = f2bf(v.w * inv);
    *(ushort4*)(qn + (size_t)pix * Dd + lane * 4) = o;
}

// ---------- K3: MFMA corr + softmax; writes PADDED xb [B][132][132][64] ----------
__global__ __launch_bounds__(256) void corr_mfma(const unsigned short* __restrict__ qn,
                                                 const unsigned short* __restrict__ kn,
                                                 const float* __restrict__ log_temp,
                                                 unsigned short* __restrict__ xb,
                                                 float* __restrict__ out) {
    __shared__ float clds[4][160 * 20];
    int wid = threadIdx.x >> 6, lane = threadIdx.x & 63;
    int tile = blockIdx.x * 4 + wid;
    int b = tile >> 10; int rem = tile & 1023; int y = rem >> 3; int x0 = (rem & 7) << 4;
    int l15 = lane & 15, quad = lane >> 4;

    const s16x8* aptr = (const s16x8*)(qn + ((size_t)(b << 14) + y * Ww + x0 + l15) * Dd + quad * 8);
    const s16x8* bptr[10];
#pragma unroll
    for (int f = 0; f < 10; f++) {
        int p = f * 16 + l15; if (p > 153) p = 153;
        int ry = p / 22, rx = p - ry * 22;
        int yy = min(max(y - 3 + ry, 0), Hh - 1);
        int xx = min(max(x0 - 3 + rx, 0), Ww - 1);
        bptr[f] = (const s16x8*)(kn + ((size_t)(b << 14) + yy * Ww + xx) * Dd + quad * 8);
    }
    f32x4 acc[10];
#pragma unroll
    for (int f = 0; f < 10; f++) acc[f] = (f32x4){0.f, 0.f, 0.f, 0.f};
#pragma unroll
    for (int k = 0; k < 8; k++) {
        s16x8 a = aptr[k * 4];
#pragma unroll
        for (int f = 0; f < 10; f++) {
            s16x8 bb = bptr[f][k * 4];
            acc[f] = __builtin_amdgcn_mfma_f32_16x16x32_bf16(a, bb, acc[f], 0, 0, 0);
        }
    }
    float* cw = clds[wid];
#pragma unroll
    for (int f = 0; f < 10; f++) {
        int n = f * 16 + l15;
        *(f32x4*)(cw + n * 20 + quad * 4) = acc[f];
    }
    __syncthreads();

    // softmax epilogue: 4 lanes per pixel
    int px = l15, part = quad;
    int x = x0 + px;
    float inv_temp = expf(-log_temp[0]);
    float vals[13];
    float vmax = -1e30f;
#pragma unroll
    for (int i = 0; i < 13; i++) {
        int s = part + 4 * i;
        if (s < 49) {
            int dy = s / 7 - 3, dx = s % 7 - 3;
            int ry = min(max(y + dy, 0), Hh - 1) - (y - 3);
            int rx = min(max(x + dx, 0), Ww - 1) - (x0 - 3);
            float v = cw[(ry * 22 + rx) * 20 + px];
            vals[i] = v;
            vmax = fmaxf(vmax, v);
        }
    }
    vmax = fmaxf(vmax, __shfl_xor(vmax, 16, 64));
    vmax = fmaxf(vmax, __shfl_xor(vmax, 32, 64));

    unsigned short* xp = xb + ((size_t)(b * WP + y + 2) * WP + x + 2) * 64;
    float se = 0.f, sey = 0.f, sex = 0.f, emax = 0.f;
#pragma unroll
    for (int i = 0; i < 13; i++) {
        int s = part + 4 * i;
        if (s < 49) {
            float e = expf((vals[i] - vmax) * inv_temp);
            se += e;
            sey += e * (float)(s / 7 - 3);
            sex += e * (float)(s % 7 - 3);
            emax = fmaxf(emax, e);
            xp[2 + s] = f2bf(vals[i]);
        }
    }
    se += __shfl_xor(se, 16, 64);  se += __shfl_xor(se, 32, 64);
    sey += __shfl_xor(sey, 16, 64); sey += __shfl_xor(sey, 32, 64);
    sex += __shfl_xor(sex, 16, 64); sex += __shfl_xor(sex, 32, 64);
    emax = fmaxf(emax, __shfl_xor(emax, 16, 64));
    emax = fmaxf(emax, __shfl_xor(emax, 32, 64));
    float inv_se = 1.0f / se;
    float dyv = sey * inv_se, dxv = sex * inv_se, conf = emax * inv_se;
    float* op = out + (size_t)b * 5 * HW + y * Ww + x;
    if (part == 0) { xp[0] = f2bf(dyv);   op[2 * HW] = dyv; }
    if (part == 1) { xp[1] = f2bf(dxv);   op[3 * HW] = dxv; }
    if (part == 2) { xp[51] = f2bf(conf); op[4 * HW] = conf; }
    if (part == 3) {
        ushort4 z = {0, 0, 0, 0};
        *(ushort4*)(xp + 52) = z;
        *(ushort4*)(xp + 56) = z;
        *(ushort4*)(xp + 60) = z;
    }
}

// ---------- K0: conv weights -> bf16 [tap][n][k] ----------
__global__ __launch_bounds__(256) void prep_weights(const float* __restrict__ w0,
                                                    const float* __restrict__ w1,
                                                    const float* __restrict__ w2,
                                                    unsigned short* __restrict__ wb0,
                                                    unsigned short* __restrict__ wb1,
                                                    unsigned short* __restrict__ wb2) {
    int t = blockIdx.x * 256 + threadIdx.x;
    if (t < 51200) {
        int tap = t >> 11; int r = t & 2047; int n = r >> 6; int k = r & 63;
        wb0[t] = (k < 52) ? f2bf(w0[n * 1300 + k * 25 + tap]) : (unsigned short)0;
    } else if (t < 76800) {
        int u = t - 51200; int tap = u >> 10; int r = u & 1023; int n = r >> 5; int k = r & 31;
        wb1[u] = f2bf(w1[n * 800 + k * 25 + tap]);
    } else if (t < 89600) {
        int u = t - 76800; int tap = u >> 9; int r = u & 511; int n = r >> 5; int k = r & 31;
        wb2[u] = (n < 2) ? f2bf(w2[n * 800 + k * 25 + tap]) : (unsigned short)0;
    }
}

// ---------- MFMA implicit-GEMM 5x5 conv, PADDED channel-last bf16, branch-free ----------
// in: [B][132][132][ICP], out: [B][132][132][OC]; wave per 16-px row tile
template <int KSTEPS, int NF, bool GELU>
__global__ __launch_bounds__(256, 4) void conv_mfma(const unsigned short* __restrict__ in,
                                                    const unsigned short* __restrict__ wb,
                                                    const float* __restrict__ bias,
                                                    unsigned short* __restrict__ outp) {
    constexpr int ICP = KSTEPS * 32;
    constexpr int OC = NF * 16;
    int wid = threadIdx.x >> 6, lane = threadIdx.x & 63;
    int tile = blockIdx.x * 4 + wid;
    int b = tile >> 10, rem = tile & 1023, y = rem >> 3, x0 = (rem & 7) << 4;
    int l15 = lane & 15, quad = lane >> 4;
    f32x4 acc[NF];
#pragma unroll
    for (int g = 0; g < NF; g++) acc[g] = (f32x4){0.f, 0.f, 0.f, 0.f};
    // base: padded coord (y+ky, x0+l15+kx); output pixel (y,x) -> padded (y+2,x+2)
    const unsigned short* abase = in + ((size_t)(b * WP + y) * WP + x0 + l15) * ICP + quad * 8;
#pragma unroll
    for (int ky = 0; ky < 5; ky++) {
#pragma unroll
        for (int kx = 0; kx < 5; kx++) {
            const s16x8* ap = (const s16x8*)(abase + ((size_t)ky * WP + kx) * ICP);
            const unsigned short* wtap = wb + (ky * 5 + kx) * (OC * ICP);
#pragma unroll
            for (int ks = 0; ks < KSTEPS; ks++) {
                s16x8 a = ap[ks * 4];
#pragma unroll
                for (int g = 0; g < NF; g++) {
                    s16x8 bb = *(const s16x8*)(wtap + (g * 16 + l15) * ICP + ks * 32 + quad * 8);
                    acc[g] = __builtin_amdgcn_mfma_f32_16x16x32_bf16(a, bb, acc[g], 0, 0, 0);
                }
            }
        }
    }
    unsigned short* obase = outp + ((size_t)(b * WP + y + 2) * WP + x0 + 2) * OC + l15;
#pragma unroll
    for (int g = 0; g < NF; g++) {
        float bv = bias[g * 16 + l15];
#pragma unroll
        for (int r = 0; r < 4; r++) {
            int m = quad * 4 + r;
            float v = acc[g][r] + bv;
            if (GELU) v = gelu_exact(v);
            obase[(size_t)m * OC + g * 16] = f2bf(v);
        }
    }
}

// ---------- final conv (32->2) MFMA + residual + sky scaling, branch-free ----------
__global__ __launch_bounds__(256, 4) void conv_final_mfma(const unsigned short* __restrict__ in,
                                                          const unsigned short* __restrict__ wb,
                                                          const float* __restrict__ bias,
                                                          float* __restrict__ out) {
    __shared__ float cl[4][16][2];
    int wid = threadIdx.x >> 6, lane = threadIdx.x & 63;
    int tile = blockIdx.x * 4 + wid;
    int b = tile >> 10, rem = tile & 1023, y = rem >> 3, x0 = (rem & 7) << 4;
    int l15 = lane & 15, quad = lane >> 4;
    f32x4 acc = (f32x4){0.f, 0.f, 0.f, 0.f};
    const unsigned short* abase = in + ((size_t)(b * WP + y) * WP + x0 + l15) * 32 + quad * 8;
#pragma unroll
    for (int ky = 0; ky < 5; ky++) {
#pragma unroll
        for (int kx = 0; kx < 5; kx++) {
            s16x8 a = *(const s16x8*)(abase + ((size_t)ky * WP + kx) * 32);
            s16x8 bb = *(const s16x8*)(wb + (ky * 5 + kx) * 512 + l15 * 32 + quad * 8);
            acc = __builtin_amdgcn_mfma_f32_16x16x32_bf16(a, bb, acc, 0, 0, 0);
        }
    }
    if (l15 < 2) {
        float bv = bias[l15];
#pragma unroll
        for (int r = 0; r < 4; r++) cl[wid][quad * 4 + r][l15] = acc[r] + bv;
    }
    __syncthreads();
    if (quad == 0) {
        size_t p5 = (size_t)b * 5 * HW + y * Ww + x0 + l15;
        float a0 = cl[wid][l15][0], a1 = cl[wid][l15][1];
        float dy = out[p5 + 2 * HW], dx = out[p5 + 3 * HW];
        out[p5] = (dx + a1) * 1.6f;        // dra
        out[p5 + HW] = (dy + a0) * 1.6f;   // ddec
    }
}

extern "C" void kernel_launch(void* const* d_in, const int* in_sizes, int n_in,
                              void* d_out, int out_size, void* d_ws, size_t ws_size,
                              hipStream_t stream) {
    const float* rub = (const float*)d_in[0];
    const float* vis = (const float*)d_in[1];
    const float* w0 = (const float*)d_in[2];
    const float* b0 = (const float*)d_in[3];
    const float* w1 = (const float*)d_in[4];
    const float* b1 = (const float*)d_in[5];
    const float* w2 = (const float*)d_in[6];
    const float* b2 = (const float*)d_in[7];
    const float* log_temp = (const float*)d_in[8];
    float* out = (float*)d_out;

    char* ws = (char*)d_ws;
    size_t off = 0;
    const size_t PADPIX = (size_t)Bb * WP * WP;     // 69,696
    unsigned short* kn = (unsigned short*)(ws + off); off += (size_t)NPIX * Dd * 2;  // 33.5MB
    unsigned short* qn = (unsigned short*)(ws + off); off += (size_t)NPIX * Dd * 2;  // 33.5MB
    unsigned short* xbp = (unsigned short*)(ws + off); off += PADPIX * 64 * 2;       // 8.9MB
    unsigned short* h1p = (unsigned short*)(ws + off); off += PADPIX * 32 * 2;       // 4.5MB
    unsigned short* h2p = (unsigned short*)(ws + off); off += PADPIX * 32 * 2;       // 4.5MB
    unsigned short* wb0 = (unsigned short*)(ws + off); off += 51200 * 2;
    unsigned short* wb1 = (unsigned short*)(ws + off); off += 25600 * 2;
    unsigned short* wb2 = (unsigned short*)(ws + off); off += 12800 * 2;

    // zero the padded activation buffers (borders must be 0; interiors overwritten)
    hipMemsetAsync(xbp, 0, PADPIX * 64 * 2, stream);
    hipMemsetAsync(h1p, 0, PADPIX * 32 * 2, stream);
    hipMemsetAsync(h2p, 0, PADPIX * 32 * 2, stream);

    prep_weights<<<350, 256, 0, stream>>>(w0, w1, w2, wb0, wb1, wb2);
    norm_vis<<<NPIX / 4, 256, 0, stream>>>(vis, kn);
    interp_norm_q<<<NPIX / 4, 256, 0, stream>>>(rub, qn);
    corr_mfma<<<1024, 256, 0, stream>>>(qn, kn, log_temp, xbp, out);
    conv_mfma<2, 2, true><<<1024, 256, 0, stream>>>(xbp, wb0, b0, h1p);
    conv_mfma<1, 2, true><<<1024, 256, 0, stream>>>(h1p, wb1, b1, h2p);
    conv_final_mfma<<<1024, 256, 0, stream>>>(h2p, wb2, b2, out);
}

// Round 5
// 254.599 us; speedup vs baseline: 1.2163x; 1.2163x over previous
//
#include <hip/hip_runtime.h>
#include <math.h>

#define Hh 128
#define Ww 128
#define Dd 256
#define Bb 4
#define HW (Hh*Ww)        // 16384
#define NPIX (Bb*HW)      // 65536
#define WP 132            // padded width/height (2-px zero ring)

typedef __attribute__((ext_vector_type(8))) short s16x8;   // 8 bf16 (4 VGPRs)
typedef __attribute__((ext_vector_type(4))) float f32x4;

// ---------- wave (64-lane) butterfly reductions ----------
__device__ __forceinline__ float wsum(float v) {
#pragma unroll
    for (int o = 32; o; o >>= 1) v += __shfl_xor(v, o, 64);
    return v;
}

// fp32 -> bf16 RNE
__device__ __forceinline__ unsigned short f2bf(float f) {
    unsigned u = __float_as_uint(f);
    u += 0x7FFF + ((u >> 16) & 1);
    return (unsigned short)(u >> 16);
}

__device__ __forceinline__ float gelu_exact(float v) {
    return 0.5f * v * (1.0f + erff(v * 0.70710678118654752f));
}

// ---------- K1: L2-normalize vis tokens -> kn [B,H,W,D] bf16 ----------
__global__ __launch_bounds__(256) void norm_vis(const float* __restrict__ vis,
                                                unsigned short* __restrict__ kn) {
    int wid = threadIdx.x >> 6, lane = threadIdx.x & 63;
    int pix = blockIdx.x * 4 + wid;
    const float4 v = *(const float4*)(vis + (size_t)pix * Dd + lane * 4);
    float ss = wsum(v.x * v.x + v.y * v.y + v.z * v.z + v.w * v.w);
    float inv = 1.0f / fmaxf(sqrtf(ss), 1e-12f);
    ushort4 o;
    o.x = f2bf(v.x * inv); o.y = f2bf(v.y * inv);
    o.z = f2bf(v.z * inv); o.w = f2bf(v.w * inv);
    *(ushort4*)(kn + (size_t)pix * Dd + lane * 4) = o;
}

// ---------- K2: bilinear-upsample rubin 64x64 -> 128x128 + L2 norm -> qn bf16 ----------
__global__ __launch_bounds__(256) void interp_norm_q(const float* __restrict__ rub,
                                                     unsigned short* __restrict__ qn) {
    int wid = threadIdx.x >> 6, lane = threadIdx.x & 63;
    int pix = blockIdx.x * 4 + wid;
    int b = pix >> 14; int yx = pix & 16383; int y = yx >> 7; int x = yx & 127;
    float sy = 0.5f * y - 0.25f;
    float sx = 0.5f * x - 0.25f;
    int y0 = (int)floorf(sy); float fy = sy - (float)y0;
    int x0 = (int)floorf(sx); float fx = sx - (float)x0;
    int y0c = max(y0, 0), y1c = min(y0 + 1, 63);
    int x0c = max(x0, 0), x1c = min(x0 + 1, 63);
    const float* base = rub + (size_t)b * 4096 * Dd;
    const float4 v00 = *(const float4*)(base + (size_t)(y0c * 64 + x0c) * Dd + lane * 4);
    const float4 v01 = *(const float4*)(base + (size_t)(y0c * 64 + x1c) * Dd + lane * 4);
    const float4 v10 = *(const float4*)(base + (size_t)(y1c * 64 + x0c) * Dd + lane * 4);
    const float4 v11 = *(const float4*)(base + (size_t)(y1c * 64 + x1c) * Dd + lane * 4);
    float w00 = (1.f - fy) * (1.f - fx), w01 = (1.f - fy) * fx;
    float w10 = fy * (1.f - fx), w11 = fy * fx;
    float4 v;
    v.x = w00 * v00.x + w01 * v01.x + w10 * v10.x + w11 * v11.x;
    v.y = w00 * v00.y + w01 * v01.y + w10 * v10.y + w11 * v11.y;
    v.z = w00 * v00.z + w01 * v01.z + w10 * v10.z + w11 * v11.z;
    v.w = w00 * v00.w + w01 * v01.w + w10 * v10.w + w11 * v11.w;
    float ss = wsum(v.x * v.x + v.y * v.y + v.z * v.z + v.w * v.w);
    float inv = 1.0f / fmaxf(sqrtf(ss), 1e-12f);
    ushort4 o;
    o.x = f2bf(v.x * inv); o.y = f2bf(v.y * inv);
    o.z = f2bf(v.z * inv); o.w = f2bf(v.w * inv);
    *(ushort4*)(qn + (size_t)pix * Dd + lane * 4) = o;
}

// ---------- K3: MFMA corr + softmax; writes PADDED xb [B][132][132][64] ----------
__global__ __launch_bounds__(256) void corr_mfma(const unsigned short* __restrict__ qn,
                                                 const unsigned short* __restrict__ kn,
                                                 const float* __restrict__ log_temp,
                                                 unsigned short* __restrict__ xb,
                                                 float* __restrict__ out) {
    __shared__ float clds[4][160 * 20];
    int wid = threadIdx.x >> 6, lane = threadIdx.x & 63;
    int tile = blockIdx.x * 4 + wid;
    int b = tile >> 10; int rem = tile & 1023; int y = rem >> 3; int x0 = (rem & 7) << 4;
    int l15 = lane & 15, quad = lane >> 4;

    const s16x8* aptr = (const s16x8*)(qn + ((size_t)(b << 14) + y * Ww + x0 + l15) * Dd + quad * 8);
    const s16x8* bptr[10];
#pragma unroll
    for (int f = 0; f < 10; f++) {
        int p = f * 16 + l15; if (p > 153) p = 153;
        int ry = p / 22, rx = p - ry * 22;
        int yy = min(max(y - 3 + ry, 0), Hh - 1);
        int xx = min(max(x0 - 3 + rx, 0), Ww - 1);
        bptr[f] = (const s16x8*)(kn + ((size_t)(b << 14) + yy * Ww + xx) * Dd + quad * 8);
    }
    f32x4 acc[10];
#pragma unroll
    for (int f = 0; f < 10; f++) acc[f] = (f32x4){0.f, 0.f, 0.f, 0.f};
#pragma unroll
    for (int k = 0; k < 8; k++) {
        s16x8 a = aptr[k * 4];
#pragma unroll
        for (int f = 0; f < 10; f++) {
            s16x8 bb = bptr[f][k * 4];
            acc[f] = __builtin_amdgcn_mfma_f32_16x16x32_bf16(a, bb, acc[f], 0, 0, 0);
        }
    }
    float* cw = clds[wid];
#pragma unroll
    for (int f = 0; f < 10; f++) {
        int n = f * 16 + l15;
        *(f32x4*)(cw + n * 20 + quad * 4) = acc[f];
    }
    __syncthreads();

    // softmax epilogue: 4 lanes per pixel
    int px = l15, part = quad;
    int x = x0 + px;
    float inv_temp = expf(-log_temp[0]);
    float vals[13];
    float vmax = -1e30f;
#pragma unroll
    for (int i = 0; i < 13; i++) {
        int s = part + 4 * i;
        if (s < 49) {
            int dy = s / 7 - 3, dx = s % 7 - 3;
            int ry = min(max(y + dy, 0), Hh - 1) - (y - 3);
            int rx = min(max(x + dx, 0), Ww - 1) - (x0 - 3);
            float v = cw[(ry * 22 + rx) * 20 + px];
            vals[i] = v;
            vmax = fmaxf(vmax, v);
        }
    }
    vmax = fmaxf(vmax, __shfl_xor(vmax, 16, 64));
    vmax = fmaxf(vmax, __shfl_xor(vmax, 32, 64));

    unsigned short* xp = xb + ((size_t)(b * WP + y + 2) * WP + x + 2) * 64;
    float se = 0.f, sey = 0.f, sex = 0.f, emax = 0.f;
#pragma unroll
    for (int i = 0; i < 13; i++) {
        int s = part + 4 * i;
        if (s < 49) {
            float e = expf((vals[i] - vmax) * inv_temp);
            se += e;
            sey += e * (float)(s / 7 - 3);
            sex += e * (float)(s % 7 - 3);
            emax = fmaxf(emax, e);
            xp[2 + s] = f2bf(vals[i]);
        }
    }
    se += __shfl_xor(se, 16, 64);  se += __shfl_xor(se, 32, 64);
    sey += __shfl_xor(sey, 16, 64); sey += __shfl_xor(sey, 32, 64);
    sex += __shfl_xor(sex, 16, 64); sex += __shfl_xor(sex, 32, 64);
    emax = fmaxf(emax, __shfl_xor(emax, 16, 64));
    emax = fmaxf(emax, __shfl_xor(emax, 32, 64));
    float inv_se = 1.0f / se;
    float dyv = sey * inv_se, dxv = sex * inv_se, conf = emax * inv_se;
    float* op = out + (size_t)b * 5 * HW + y * Ww + x;
    if (part == 0) { xp[0] = f2bf(dyv);   op[2 * HW] = dyv; }
    if (part == 1) { xp[1] = f2bf(dxv);   op[3 * HW] = dxv; }
    if (part == 2) { xp[51] = f2bf(conf); op[4 * HW] = conf; }
    if (part == 3) {
        ushort4 z = {0, 0, 0, 0};
        *(ushort4*)(xp + 52) = z;
        *(ushort4*)(xp + 56) = z;
        *(ushort4*)(xp + 60) = z;
    }
}

// ---------- K0: conv weights -> bf16 [tap][n][k] ----------
__global__ __launch_bounds__(256) void prep_weights(const float* __restrict__ w0,
                                                    const float* __restrict__ w1,
                                                    const float* __restrict__ w2,
                                                    unsigned short* __restrict__ wb0,
                                                    unsigned short* __restrict__ wb1,
                                                    unsigned short* __restrict__ wb2) {
    int t = blockIdx.x * 256 + threadIdx.x;
    if (t < 51200) {
        int tap = t >> 11; int r = t & 2047; int n = r >> 6; int k = r & 63;
        wb0[t] = (k < 52) ? f2bf(w0[n * 1300 + k * 25 + tap]) : (unsigned short)0;
    } else if (t < 76800) {
        int u = t - 51200; int tap = u >> 10; int r = u & 1023; int n = r >> 5; int k = r & 31;
        wb1[u] = f2bf(w1[n * 800 + k * 25 + tap]);
    } else if (t < 89600) {
        int u = t - 76800; int tap = u >> 9; int r = u & 511; int n = r >> 5; int k = r & 31;
        wb2[u] = (n < 2) ? f2bf(w2[n * 800 + k * 25 + tap]) : (unsigned short)0;
    }
}

// ---------- LDS row-block MFMA conv: block = 1 output row (128 px), 4 waves x M=32 ----------
// in: padded [B][132][132][ICP] bf16; weights wb: [25][OC][ICP] bf16
// LDS: A = one padded input row (132 px), W = 5-tap chunk; +1-granule padded strides
template <int ICP, int OC, bool GELU>
__global__ __launch_bounds__(256) void conv_lds(const unsigned short* __restrict__ in,
                                                const unsigned short* __restrict__ wb,
                                                const float* __restrict__ bias,
                                                unsigned short* __restrict__ outp) {
    constexpr int AG = ICP / 8;        // 16B granules per pixel
    constexpr int ASTR = AG + 1;       // padded stride (granules)
    constexpr int WSTR = AG + 1;
    constexpr int NF = OC / 16;
    constexpr int KS = ICP / 32;
    constexpr int ABYTES = 132 * ASTR * 16;
    constexpr int WBYTES = 5 * OC * WSTR * 16;
    __shared__ char smem[ABYTES + WBYTES];
    uint4* aLDS = (uint4*)smem;
    uint4* wLDS = (uint4*)(smem + ABYTES);

    int tid = threadIdx.x;
    int wid = tid >> 6, lane = tid & 63, l15 = lane & 15, quad = lane >> 4;
    int blk = blockIdx.x;              // 0..511
    int b = blk >> 7, y = blk & 127;

    f32x4 acc0[NF], acc1[NF];
#pragma unroll
    for (int g = 0; g < NF; g++) { acc0[g] = (f32x4){0,0,0,0}; acc1[g] = (f32x4){0,0,0,0}; }

    for (int ky = 0; ky < 5; ky++) {
        __syncthreads();
        // stage A: padded row y+ky (full 132 px, contiguous)
        const uint4* asrc = (const uint4*)(in + ((size_t)(b * WP + y + ky) * WP) * ICP);
        constexpr int AGR = 132 * AG;
#pragma unroll
        for (int i = 0; i < (AGR + 255) / 256; i++) {
            int g = i * 256 + tid;
            if (g < AGR) {
                int px = g / AG, sub = g % AG;
                aLDS[px * ASTR + sub] = asrc[g];
            }
        }
        // stage W: taps ky*5 .. ky*5+4 (contiguous)
        const uint4* wsrc = (const uint4*)(wb + (size_t)(ky * 5) * OC * ICP);
        constexpr int WGR = 5 * OC * AG;
#pragma unroll
        for (int i = 0; i < (WGR + 255) / 256; i++) {
            int g = i * 256 + tid;
            if (g < WGR) {
                int nl = g / AG, sub = g % AG;
                wLDS[nl * WSTR + sub] = wsrc[g];
            }
        }
        __syncthreads();
        // compute: wave handles px 32*wid .. 32*wid+31 (2 M-frags)
#pragma unroll
        for (int kx = 0; kx < 5; kx++) {
#pragma unroll
            for (int ks = 0; ks < KS; ks++) {
                int abyte = ((32 * wid + l15 + kx) * ASTR + ks * 4 + quad) * 16;
                s16x8 a0 = *(const s16x8*)(smem + abyte);
                s16x8 a1 = *(const s16x8*)(smem + abyte + 16 * ASTR * 16);
#pragma unroll
                for (int g = 0; g < NF; g++) {
                    int wbyte = ABYTES + ((kx * OC + g * 16 + l15) * WSTR + ks * 4 + quad) * 16;
                    s16x8 bf = *(const s16x8*)(smem + wbyte);
                    acc0[g] = __builtin_amdgcn_mfma_f32_16x16x32_bf16(a0, bf, acc0[g], 0, 0, 0);
                    acc1[g] = __builtin_amdgcn_mfma_f32_16x16x32_bf16(a1, bf, acc1[g], 0, 0, 0);
                }
            }
        }
    }
    // epilogue: C/D m = quad*4+r (pixel within 16), n = l15 (oc)
    size_t orow = ((size_t)(b * WP + y + 2) * WP + 2) * OC;
#pragma unroll
    for (int g = 0; g < NF; g++) {
        float bv = bias[g * 16 + l15];
#pragma unroll
        for (int r = 0; r < 4; r++) {
            int px0 = 32 * wid + quad * 4 + r;
            float v0 = acc0[g][r] + bv;
            float v1 = acc1[g][r] + bv;
            if (GELU) { v0 = gelu_exact(v0); v1 = gelu_exact(v1); }
            outp[orow + (size_t)px0 * OC + g * 16 + l15] = f2bf(v0);
            outp[orow + (size_t)(px0 + 16) * OC + g * 16 + l15] = f2bf(v1);
        }
    }
}

// ---------- final conv (32->2, OC padded 16) LDS row-block + residual + sky scaling ----------
__global__ __launch_bounds__(256) void conv_final_lds(const unsigned short* __restrict__ in,
                                                      const unsigned short* __restrict__ wb,
                                                      const float* __restrict__ bias,
                                                      float* __restrict__ out) {
    constexpr int ICP = 32, OC = 16;
    constexpr int AG = 4, ASTR = 5, WSTR = 5;
    constexpr int ABYTES = 132 * ASTR * 16;     // 10560
    constexpr int WBYTES = 5 * OC * WSTR * 16;  // 6400
    __shared__ char smem[ABYTES + WBYTES];
    __shared__ float cl[4][32][2];
    uint4* aLDS = (uint4*)smem;
    uint4* wLDS = (uint4*)(smem + ABYTES);

    int tid = threadIdx.x;
    int wid = tid >> 6, lane = tid & 63, l15 = lane & 15, quad = lane >> 4;
    int blk = blockIdx.x;
    int b = blk >> 7, y = blk & 127;

    f32x4 acc0 = (f32x4){0,0,0,0}, acc1 = (f32x4){0,0,0,0};

    for (int ky = 0; ky < 5; ky++) {
        __syncthreads();
        const uint4* asrc = (const uint4*)(in + ((size_t)(b * WP + y + ky) * WP) * ICP);
        constexpr int AGR = 132 * AG;   // 528
#pragma unroll
        for (int i = 0; i < 3; i++) {
            int g = i * 256 + tid;
            if (g < AGR) {
                int px = g / AG, sub = g % AG;
                aLDS[px * ASTR + sub] = asrc[g];
            }
        }
        const uint4* wsrc = (const uint4*)(wb + (size_t)(ky * 5) * OC * ICP);
        constexpr int WGR = 5 * OC * AG;  // 320
#pragma unroll
        for (int i = 0; i < 2; i++) {
            int g = i * 256 + tid;
            if (g < WGR) {
                int nl = g / AG, sub = g % AG;
                wLDS[nl * WSTR + sub] = wsrc[g];
            }
        }
        __syncthreads();
#pragma unroll
        for (int kx = 0; kx < 5; kx++) {
            int abyte = ((32 * wid + l15 + kx) * ASTR + quad) * 16;
            s16x8 a0 = *(const s16x8*)(smem + abyte);
            s16x8 a1 = *(const s16x8*)(smem + abyte + 16 * ASTR * 16);
            int wbyte = ABYTES + ((kx * OC + l15) * WSTR + quad) * 16;
            s16x8 bf = *(const s16x8*)(smem + wbyte);
            acc0 = __builtin_amdgcn_mfma_f32_16x16x32_bf16(a0, bf, acc0, 0, 0, 0);
            acc1 = __builtin_amdgcn_mfma_f32_16x16x32_bf16(a1, bf, acc1, 0, 0, 0);
        }
    }
    if (l15 < 2) {
        float bv = bias[l15];
#pragma unroll
        for (int r = 0; r < 4; r++) {
            cl[wid][quad * 4 + r][l15] = acc0[r] + bv;
            cl[wid][16 + quad * 4 + r][l15] = acc1[r] + bv;
        }
    }
    __syncthreads();
    if (lane < 32) {
        int px = lane;
        size_t p5 = (size_t)b * 5 * HW + y * Ww + 32 * wid + px;
        float a0 = cl[wid][px][0], a1 = cl[wid][px][1];
        float dy = out[p5 + 2 * HW], dx = out[p5 + 3 * HW];
        out[p5] = (dx + a1) * 1.6f;        // dra
        out[p5 + HW] = (dy + a0) * 1.6f;   // ddec
    }
}

extern "C" void kernel_launch(void* const* d_in, const int* in_sizes, int n_in,
                              void* d_out, int out_size, void* d_ws, size_t ws_size,
                              hipStream_t stream) {
    const float* rub = (const float*)d_in[0];
    const float* vis = (const float*)d_in[1];
    const float* w0 = (const float*)d_in[2];
    const float* b0 = (const float*)d_in[3];
    const float* w1 = (const float*)d_in[4];
    const float* b1 = (const float*)d_in[5];
    const float* w2 = (const float*)d_in[6];
    const float* b2 = (const float*)d_in[7];
    const float* log_temp = (const float*)d_in[8];
    float* out = (float*)d_out;

    char* ws = (char*)d_ws;
    size_t off = 0;
    const size_t PADPIX = (size_t)Bb * WP * WP;     // 69,696
    unsigned short* kn = (unsigned short*)(ws + off); off += (size_t)NPIX * Dd * 2;  // 33.5MB
    unsigned short* qn = (unsigned short*)(ws + off); off += (size_t)NPIX * Dd * 2;  // 33.5MB
    unsigned short* xbp = (unsigned short*)(ws + off); off += PADPIX * 64 * 2;       // 8.9MB
    unsigned short* h1p = (unsigned short*)(ws + off); off += PADPIX * 32 * 2;       // 4.5MB
    unsigned short* h2p = (unsigned short*)(ws + off); off += PADPIX * 32 * 2;       // 4.5MB
    unsigned short* wb0 = (unsigned short*)(ws + off); off += 51200 * 2;
    unsigned short* wb1 = (unsigned short*)(ws + off); off += 25600 * 2;
    unsigned short* wb2 = (unsigned short*)(ws + off); off += 12800 * 2;

    // zero the padded activation buffers (borders must be 0; interiors overwritten)
    hipMemsetAsync(xbp, 0, PADPIX * 64 * 2, stream);
    hipMemsetAsync(h1p, 0, PADPIX * 32 * 2, stream);
    hipMemsetAsync(h2p, 0, PADPIX * 32 * 2, stream);

    prep_weights<<<350, 256, 0, stream>>>(w0, w1, w2, wb0, wb1, wb2);
    norm_vis<<<NPIX / 4, 256, 0, stream>>>(vis, kn);
    interp_norm_q<<<NPIX / 4, 256, 0, stream>>>(rub, qn);
    corr_mfma<<<1024, 256, 0, stream>>>(qn, kn, log_temp, xbp, out);
    conv_lds<64, 32, true><<<512, 256, 0, stream>>>(xbp, wb0, b0, h1p);
    conv_lds<32, 32, true><<<512, 256, 0, stream>>>(h1p, wb1, b1, h2p);
    conv_final_lds<<<512, 256, 0, stream>>>(h2p, wb2, b2, out);
}

// Round 6
// 230.857 us; speedup vs baseline: 1.3414x; 1.1028x over previous
//
#include <hip/hip_runtime.h>
#include <math.h>

#define Hh 128
#define Ww 128
#define Dd 256
#define Bb 4
#define HW (Hh*Ww)        // 16384
#define NPIX (Bb*HW)      // 65536
#define WP 132            // padded width/height (2-px zero ring)

typedef __attribute__((ext_vector_type(8))) short s16x8;   // 8 bf16 (4 VGPRs)
typedef __attribute__((ext_vector_type(4))) float f32x4;

__device__ __forceinline__ float wsum(float v) {
#pragma unroll
    for (int o = 32; o; o >>= 1) v += __shfl_xor(v, o, 64);
    return v;
}

__device__ __forceinline__ unsigned short f2bf(float f) {
    unsigned u = __float_as_uint(f);
    u += 0x7FFF + ((u >> 16) & 1);
    return (unsigned short)(u >> 16);
}

__device__ __forceinline__ float gelu_exact(float v) {
    return 0.5f * v * (1.0f + erff(v * 0.70710678118654752f));
}

// ---------- K0: zero padded activation buffers + transpose conv weights ----------
// zero region: 1,115,136 uint4 granules (xbp+h1p+h2p contiguous)
#define ZGRAN 1115136
__global__ __launch_bounds__(256) void setup_fill(const float* __restrict__ w0,
                                                  const float* __restrict__ w1,
                                                  const float* __restrict__ w2,
                                                  unsigned short* __restrict__ wb0,
                                                  unsigned short* __restrict__ wb1,
                                                  unsigned short* __restrict__ wb2,
                                                  uint4* __restrict__ zbase) {
    int t = blockIdx.x * 256 + threadIdx.x;
    if (t < ZGRAN) {
        zbase[t] = (uint4){0, 0, 0, 0};
        return;
    }
    int u = t - ZGRAN;
    if (u < 51200) {
        int tap = u >> 11; int r = u & 2047; int n = r >> 6; int k = r & 63;
        wb0[u] = (k < 52) ? f2bf(w0[n * 1300 + k * 25 + tap]) : (unsigned short)0;
    } else if (u < 76800) {
        int v = u - 51200; int tap = v >> 10; int r = v & 1023; int n = r >> 5; int k = r & 31;
        wb1[v] = f2bf(w1[n * 800 + k * 25 + tap]);
    } else if (u < 89600) {
        int v = u - 76800; int tap = v >> 9; int r = v & 511; int n = r >> 5; int k = r & 31;
        wb2[v] = (n < 2) ? f2bf(w2[n * 800 + k * 25 + tap]) : (unsigned short)0;
    }
}

// ---------- K1: fused normalize: blocks <16384 vis->kn ; >=16384 rubin-interp->qn ----------
__global__ __launch_bounds__(256) void norm_fused(const float* __restrict__ vis,
                                                  const float* __restrict__ rub,
                                                  unsigned short* __restrict__ kn,
                                                  unsigned short* __restrict__ qn) {
    int wid = threadIdx.x >> 6, lane = threadIdx.x & 63;
    int blk = blockIdx.x;
    if (blk < 16384) {
        int pix = blk * 4 + wid;
        const float4 v = *(const float4*)(vis + (size_t)pix * Dd + lane * 4);
        float ss = wsum(v.x * v.x + v.y * v.y + v.z * v.z + v.w * v.w);
        float inv = 1.0f / fmaxf(sqrtf(ss), 1e-12f);
        ushort4 o;
        o.x = f2bf(v.x * inv); o.y = f2bf(v.y * inv);
        o.z = f2bf(v.z * inv); o.w = f2bf(v.w * inv);
        *(ushort4*)(kn + (size_t)pix * Dd + lane * 4) = o;
    } else {
        int pix = (blk - 16384) * 4 + wid;
        int b = pix >> 14; int yx = pix & 16383; int y = yx >> 7; int x = yx & 127;
        float sy = 0.5f * y - 0.25f;
        float sx = 0.5f * x - 0.25f;
        int y0 = (int)floorf(sy); float fy = sy - (float)y0;
        int x0 = (int)floorf(sx); float fx = sx - (float)x0;
        int y0c = max(y0, 0), y1c = min(y0 + 1, 63);
        int x0c = max(x0, 0), x1c = min(x0 + 1, 63);
        const float* base = rub + (size_t)b * 4096 * Dd;
        const float4 v00 = *(const float4*)(base + (size_t)(y0c * 64 + x0c) * Dd + lane * 4);
        const float4 v01 = *(const float4*)(base + (size_t)(y0c * 64 + x1c) * Dd + lane * 4);
        const float4 v10 = *(const float4*)(base + (size_t)(y1c * 64 + x0c) * Dd + lane * 4);
        const float4 v11 = *(const float4*)(base + (size_t)(y1c * 64 + x1c) * Dd + lane * 4);
        float w00 = (1.f - fy) * (1.f - fx), w01 = (1.f - fy) * fx;
        float w10 = fy * (1.f - fx), w11 = fy * fx;
        float4 v;
        v.x = w00 * v00.x + w01 * v01.x + w10 * v10.x + w11 * v11.x;
        v.y = w00 * v00.y + w01 * v01.y + w10 * v10.y + w11 * v11.y;
        v.z = w00 * v00.z + w01 * v01.z + w10 * v10.z + w11 * v11.z;
        v.w = w00 * v00.w + w01 * v01.w + w10 * v10.w + w11 * v11.w;
        float ss = wsum(v.x * v.x + v.y * v.y + v.z * v.z + v.w * v.w);
        float inv = 1.0f / fmaxf(sqrtf(ss), 1e-12f);
        ushort4 o;
        o.x = f2bf(v.x * inv); o.y = f2bf(v.y * inv);
        o.z = f2bf(v.z * inv); o.w = f2bf(v.w * inv);
        *(ushort4*)(qn + (size_t)pix * Dd + lane * 4) = o;
    }
}

// ---------- K2: 2D-tiled LDS corr + shuffle softmax ----------
// block = 16x16 output pixels (16 waves, one row each); kn neighborhood 22x22 staged
// in LDS in 8 channel-chunks of 32. C[m=pixel-in-row][n=offset-position(7x22)].
__global__ __launch_bounds__(1024) void corr_block(const unsigned short* __restrict__ qn,
                                                   const unsigned short* __restrict__ kn,
                                                   const float* __restrict__ log_temp,
                                                   unsigned short* __restrict__ xb,
                                                   float* __restrict__ out) {
    __shared__ char smem[484 * 5 * 16];   // 22x22 px, 4+1 granules of 16B each = 38720 B
    int tid = threadIdx.x;
    int wid = tid >> 6, lane = tid & 63, l15 = lane & 15, quad = lane >> 4;
    int blk = blockIdx.x;
    int b = blk >> 6, rem = blk & 63;
    int y0 = ((rem >> 3) & 7) << 4, x0 = (rem & 7) << 4;
    int y = y0 + wid;

    // staging precompute: slot0 (always), slot1 (tid < 912)
    const unsigned short* src0; int dst0;
    const unsigned short* src1 = nullptr; int dst1 = 0;
    bool hav1;
    {
        int g = tid;
        int px = g >> 2, sub = g & 3;
        int ry = px / 22, rx = px - ry * 22;
        int yy = min(max(y0 - 3 + ry, 0), 127);
        int xx = min(max(x0 - 3 + rx, 0), 127);
        src0 = kn + ((size_t)(b << 14) + yy * 128 + xx) * 256 + sub * 8;
        dst0 = (px * 5 + sub) * 16;
        g = 1024 + tid;
        hav1 = (g < 1936);
        int gc = hav1 ? g : 1935;
        px = gc >> 2; sub = gc & 3;
        ry = px / 22; rx = px - ry * 22;
        yy = min(max(y0 - 3 + ry, 0), 127);
        xx = min(max(x0 - 3 + rx, 0), 127);
        src1 = kn + ((size_t)(b << 14) + yy * 128 + xx) * 256 + sub * 8;
        dst1 = (px * 5 + sub) * 16;
    }
    // B-frag LDS offsets per frag (position p = f*16+l15, clamped)
    int lpixoff[10];
#pragma unroll
    for (int f = 0; f < 10; f++) {
        int p = min(f * 16 + l15, 153);
        int pr = p / 22, pc = p - pr * 22;
        lpixoff[f] = (((wid + pr) * 22 + pc) * 5 + quad) * 16;
    }
    const unsigned short* aptr = qn + ((size_t)(b << 14) + y * 128 + x0 + l15) * 256 + quad * 8;

    f32x4 acc[10];
#pragma unroll
    for (int f = 0; f < 10; f++) acc[f] = (f32x4){0.f, 0.f, 0.f, 0.f};

    // prefetch chunk 0
    uint4 v0 = *(const uint4*)src0;
    uint4 v1 = *(const uint4*)src1;
    s16x8 an = *(const s16x8*)aptr;
    for (int c = 0; c < 8; c++) {
        uint4 w0v = v0, w1v = v1;
        s16x8 a = an;
        if (c < 7) {
            v0 = *(const uint4*)(src0 + (c + 1) * 32);
            v1 = *(const uint4*)(src1 + (c + 1) * 32);
            an = *(const s16x8*)(aptr + (c + 1) * 32);
        }
        __syncthreads();                       // previous chunk's compute done
        *(uint4*)(smem + dst0) = w0v;
        if (hav1) *(uint4*)(smem + dst1) = w1v;
        __syncthreads();
#pragma unroll
        for (int f = 0; f < 10; f++) {
            s16x8 bf = *(const s16x8*)(smem + lpixoff[f]);
            acc[f] = __builtin_amdgcn_mfma_f32_16x16x32_bf16(a, bf, acc[f], 0, 0, 0);
        }
    }

    // ---- epilogue: softmax per pixel via width-16 shuffles ----
    // lane holds D[m = quad*4 + i][n = f*16 + l15]; pixel p = quad*4+i lives in this quad-group
    float inv_temp = expf(-log_temp[0]);
    float vmax[4] = {-1e30f, -1e30f, -1e30f, -1e30f};
#pragma unroll
    for (int f = 0; f < 10; f++) {
        int n = f * 16 + l15;
        if (n <= 153) {
            int dy = n / 22 - 3;
            int rx = n - (dy + 3) * 22;
#pragma unroll
            for (int i = 0; i < 4; i++) {
                int m = quad * 4 + i;
                int dx = rx - m - 3;
                if ((unsigned)(dx + 3) <= 6u) vmax[i] = fmaxf(vmax[i], acc[f][i]);
            }
        }
    }
#pragma unroll
    for (int o = 1; o <= 8; o <<= 1) {
#pragma unroll
        for (int i = 0; i < 4; i++) vmax[i] = fmaxf(vmax[i], __shfl_xor(vmax[i], o, 64));
    }
    float se[4] = {0, 0, 0, 0}, sey[4] = {0, 0, 0, 0}, sex[4] = {0, 0, 0, 0}, emax[4] = {0, 0, 0, 0};
    unsigned short* xrow = xb + ((size_t)(b * WP + y + 2) * WP + x0 + 2) * 64;
#pragma unroll
    for (int f = 0; f < 10; f++) {
        int n = f * 16 + l15;
        if (n <= 153) {
            int dy = n / 22 - 3;
            int rx = n - (dy + 3) * 22;
#pragma unroll
            for (int i = 0; i < 4; i++) {
                int m = quad * 4 + i;
                int dx = rx - m - 3;
                if ((unsigned)(dx + 3) <= 6u) {
                    float v = acc[f][i];
                    float e = expf((v - vmax[i]) * inv_temp);
                    se[i] += e;
                    sey[i] += e * (float)dy;
                    sex[i] += e * (float)dx;
                    emax[i] = fmaxf(emax[i], e);
                    xrow[(size_t)m * 64 + 2 + (dy + 3) * 7 + (dx + 3)] = f2bf(v);
                }
            }
        }
    }
#pragma unroll
    for (int o = 1; o <= 8; o <<= 1) {
#pragma unroll
        for (int i = 0; i < 4; i++) {
            se[i] += __shfl_xor(se[i], o, 64);
            sey[i] += __shfl_xor(sey[i], o, 64);
            sex[i] += __shfl_xor(sex[i], o, 64);
            emax[i] = fmaxf(emax[i], __shfl_xor(emax[i], o, 64));
        }
    }
    if (l15 == 0) {
#pragma unroll
        for (int i = 0; i < 4; i++) {
            int m = quad * 4 + i;
            float inv_se = 1.0f / se[i];
            float dyv = sey[i] * inv_se, dxv = sex[i] * inv_se, conf = emax[i] * inv_se;
            unsigned short* xp = xrow + (size_t)m * 64;
            xp[0] = f2bf(dyv); xp[1] = f2bf(dxv); xp[51] = f2bf(conf);
            float* op = out + (size_t)b * 5 * HW + y * 128 + x0 + m;
            op[2 * HW] = dyv; op[3 * HW] = dxv; op[4 * HW] = conf;
        }
    }
}

// ---------- LDS row-block MFMA conv (unchanged from R5) ----------
template <int ICP, int OC, bool GELU>
__global__ __launch_bounds__(256) void conv_lds(const unsigned short* __restrict__ in,
                                                const unsigned short* __restrict__ wb,
                                                const float* __restrict__ bias,
                                                unsigned short* __restrict__ outp) {
    constexpr int AG = ICP / 8;
    constexpr int ASTR = AG + 1;
    constexpr int WSTR = AG + 1;
    constexpr int NF = OC / 16;
    constexpr int KS = ICP / 32;
    constexpr int ABYTES = 132 * ASTR * 16;
    constexpr int WBYTES = 5 * OC * WSTR * 16;
    __shared__ char smem[ABYTES + WBYTES];
    uint4* aLDS = (uint4*)smem;
    uint4* wLDS = (uint4*)(smem + ABYTES);

    int tid = threadIdx.x;
    int wid = tid >> 6, lane = tid & 63, l15 = lane & 15, quad = lane >> 4;
    int blk = blockIdx.x;
    int b = blk >> 7, y = blk & 127;

    f32x4 acc0[NF], acc1[NF];
#pragma unroll
    for (int g = 0; g < NF; g++) { acc0[g] = (f32x4){0,0,0,0}; acc1[g] = (f32x4){0,0,0,0}; }

    for (int ky = 0; ky < 5; ky++) {
        __syncthreads();
        const uint4* asrc = (const uint4*)(in + ((size_t)(b * WP + y + ky) * WP) * ICP);
        constexpr int AGR = 132 * AG;
#pragma unroll
        for (int i = 0; i < (AGR + 255) / 256; i++) {
            int g = i * 256 + tid;
            if (g < AGR) {
                int px = g / AG, sub = g % AG;
                aLDS[px * ASTR + sub] = asrc[g];
            }
        }
        const uint4* wsrc = (const uint4*)(wb + (size_t)(ky * 5) * OC * ICP);
        constexpr int WGR = 5 * OC * AG;
#pragma unroll
        for (int i = 0; i < (WGR + 255) / 256; i++) {
            int g = i * 256 + tid;
            if (g < WGR) {
                int nl = g / AG, sub = g % AG;
                wLDS[nl * WSTR + sub] = wsrc[g];
            }
        }
        __syncthreads();
#pragma unroll
        for (int kx = 0; kx < 5; kx++) {
#pragma unroll
            for (int ks = 0; ks < KS; ks++) {
                int abyte = ((32 * wid + l15 + kx) * ASTR + ks * 4 + quad) * 16;
                s16x8 a0 = *(const s16x8*)(smem + abyte);
                s16x8 a1 = *(const s16x8*)(smem + abyte + 16 * ASTR * 16);
#pragma unroll
                for (int g = 0; g < NF; g++) {
                    int wbyte = ABYTES + ((kx * OC + g * 16 + l15) * WSTR + ks * 4 + quad) * 16;
                    s16x8 bf = *(const s16x8*)(smem + wbyte);
                    acc0[g] = __builtin_amdgcn_mfma_f32_16x16x32_bf16(a0, bf, acc0[g], 0, 0, 0);
                    acc1[g] = __builtin_amdgcn_mfma_f32_16x16x32_bf16(a1, bf, acc1[g], 0, 0, 0);
                }
            }
        }
    }
    size_t orow = ((size_t)(b * WP + y + 2) * WP + 2) * OC;
#pragma unroll
    for (int g = 0; g < NF; g++) {
        float bv = bias[g * 16 + l15];
#pragma unroll
        for (int r = 0; r < 4; r++) {
            int px0 = 32 * wid + quad * 4 + r;
            float v0 = acc0[g][r] + bv;
            float v1 = acc1[g][r] + bv;
            if (GELU) { v0 = gelu_exact(v0); v1 = gelu_exact(v1); }
            outp[orow + (size_t)px0 * OC + g * 16 + l15] = f2bf(v0);
            outp[orow + (size_t)(px0 + 16) * OC + g * 16 + l15] = f2bf(v1);
        }
    }
}

// ---------- final conv (32->2) LDS row-block + residual + sky scaling (unchanged) ----------
__global__ __launch_bounds__(256) void conv_final_lds(const unsigned short* __restrict__ in,
                                                      const unsigned short* __restrict__ wb,
                                                      const float* __restrict__ bias,
                                                      float* __restrict__ out) {
    constexpr int ICP = 32, OC = 16;
    constexpr int AG = 4, ASTR = 5, WSTR = 5;
    constexpr int ABYTES = 132 * ASTR * 16;
    constexpr int WBYTES = 5 * OC * WSTR * 16;
    __shared__ char smem[ABYTES + WBYTES];
    __shared__ float cl[4][32][2];
    uint4* aLDS = (uint4*)smem;
    uint4* wLDS = (uint4*)(smem + ABYTES);

    int tid = threadIdx.x;
    int wid = tid >> 6, lane = tid & 63, l15 = lane & 15, quad = lane >> 4;
    int blk = blockIdx.x;
    int b = blk >> 7, y = blk & 127;

    f32x4 acc0 = (f32x4){0,0,0,0}, acc1 = (f32x4){0,0,0,0};

    for (int ky = 0; ky < 5; ky++) {
        __syncthreads();
        const uint4* asrc = (const uint4*)(in + ((size_t)(b * WP + y + ky) * WP) * ICP);
        constexpr int AGR = 132 * AG;
#pragma unroll
        for (int i = 0; i < 3; i++) {
            int g = i * 256 + tid;
            if (g < AGR) {
                int px = g / AG, sub = g % AG;
                aLDS[px * ASTR + sub] = asrc[g];
            }
        }
        const uint4* wsrc = (const uint4*)(wb + (size_t)(ky * 5) * OC * ICP);
        constexpr int WGR = 5 * OC * AG;
#pragma unroll
        for (int i = 0; i < 2; i++) {
            int g = i * 256 + tid;
            if (g < WGR) {
                int nl = g / AG, sub = g % AG;
                wLDS[nl * WSTR + sub] = wsrc[g];
            }
        }
        __syncthreads();
#pragma unroll
        for (int kx = 0; kx < 5; kx++) {
            int abyte = ((32 * wid + l15 + kx) * ASTR + quad) * 16;
            s16x8 a0 = *(const s16x8*)(smem + abyte);
            s16x8 a1 = *(const s16x8*)(smem + abyte + 16 * ASTR * 16);
            int wbyte = ABYTES + ((kx * OC + l15) * WSTR + quad) * 16;
            s16x8 bf = *(const s16x8*)(smem + wbyte);
            acc0 = __builtin_amdgcn_mfma_f32_16x16x32_bf16(a0, bf, acc0, 0, 0, 0);
            acc1 = __builtin_amdgcn_mfma_f32_16x16x32_bf16(a1, bf, acc1, 0, 0, 0);
        }
    }
    if (l15 < 2) {
        float bv = bias[l15];
#pragma unroll
        for (int r = 0; r < 4; r++) {
            cl[wid][quad * 4 + r][l15] = acc0[r] + bv;
            cl[wid][16 + quad * 4 + r][l15] = acc1[r] + bv;
        }
    }
    __syncthreads();
    if (lane < 32) {
        int px = lane;
        size_t p5 = (size_t)b * 5 * HW + y * Ww + 32 * wid + px;
        float a0 = cl[wid][px][0], a1 = cl[wid][px][1];
        float dy = out[p5 + 2 * HW], dx = out[p5 + 3 * HW];
        out[p5] = (dx + a1) * 1.6f;        // dra
        out[p5 + HW] = (dy + a0) * 1.6f;   // ddec
    }
}

extern "C" void kernel_launch(void* const* d_in, const int* in_sizes, int n_in,
                              void* d_out, int out_size, void* d_ws, size_t ws_size,
                              hipStream_t stream) {
    const float* rub = (const float*)d_in[0];
    const float* vis = (const float*)d_in[1];
    const float* w0 = (const float*)d_in[2];
    const float* b0 = (const float*)d_in[3];
    const float* w1 = (const float*)d_in[4];
    const float* b1 = (const float*)d_in[5];
    const float* w2 = (const float*)d_in[6];
    const float* b2 = (const float*)d_in[7];
    const float* log_temp = (const float*)d_in[8];
    float* out = (float*)d_out;

    char* ws = (char*)d_ws;
    size_t off = 0;
    const size_t PADPIX = (size_t)Bb * WP * WP;     // 69,696
    unsigned short* kn = (unsigned short*)(ws + off); off += (size_t)NPIX * Dd * 2;  // 33.5MB
    unsigned short* qn = (unsigned short*)(ws + off); off += (size_t)NPIX * Dd * 2;  // 33.5MB
    unsigned short* xbp = (unsigned short*)(ws + off); off += PADPIX * 64 * 2;       // contiguous
    unsigned short* h1p = (unsigned short*)(ws + off); off += PADPIX * 32 * 2;       //  zero
    unsigned short* h2p = (unsigned short*)(ws + off); off += PADPIX * 32 * 2;       //  region
    unsigned short* wb0 = (unsigned short*)(ws + off); off += 51200 * 2;
    unsigned short* wb1 = (unsigned short*)(ws + off); off += 25600 * 2;
    unsigned short* wb2 = (unsigned short*)(ws + off); off += 12800 * 2;

    // K0: zero xbp/h1p/h2p (ZGRAN uint4s) + weight transpose; 4706*256 = exact thread count
    setup_fill<<<4706, 256, 0, stream>>>(w0, w1, w2, wb0, wb1, wb2, (uint4*)xbp);
    norm_fused<<<32768, 256, 0, stream>>>(vis, rub, kn, qn);
    corr_block<<<256, 1024, 0, stream>>>(qn, kn, log_temp, xbp, out);
    conv_lds<64, 32, true><<<512, 256, 0, stream>>>(xbp, wb0, b0, h1p);
    conv_lds<32, 32, true><<<512, 256, 0, stream>>>(h1p, wb1, b1, h2p);
    conv_final_lds<<<512, 256, 0, stream>>>(h2p, wb2, b2, out);
}

// Round 7
// 214.371 us; speedup vs baseline: 1.4446x; 1.0769x over previous
//
#include <hip/hip_runtime.h>
#include <math.h>

#define Hh 128
#define Ww 128
#define Dd 256
#define Bb 4
#define HW (Hh*Ww)        // 16384
#define NPIX (Bb*HW)      // 65536
#define WP 132            // padded width/height (2-px zero ring)

typedef __attribute__((ext_vector_type(8))) short s16x8;   // 8 bf16 (4 VGPRs)
typedef __attribute__((ext_vector_type(4))) float f32x4;

__device__ __forceinline__ unsigned short f2bf(float f) {
    unsigned u = __float_as_uint(f);
    u += 0x7FFF + ((u >> 16) & 1);
    return (unsigned short)(u >> 16);
}

__device__ __forceinline__ float gelu_exact(float v) {
    return 0.5f * v * (1.0f + erff(v * 0.70710678118654752f));
}

// ---------- K0: zero padded activation buffers + transpose conv weights ----------
#define ZGRAN 1115136
__global__ __launch_bounds__(256) void setup_fill(const float* __restrict__ w0,
                                                  const float* __restrict__ w1,
                                                  const float* __restrict__ w2,
                                                  unsigned short* __restrict__ wb0,
                                                  unsigned short* __restrict__ wb1,
                                                  unsigned short* __restrict__ wb2,
                                                  uint4* __restrict__ zbase) {
    int t = blockIdx.x * 256 + threadIdx.x;
    if (t < ZGRAN) {
        zbase[t] = (uint4){0, 0, 0, 0};
        return;
    }
    int u = t - ZGRAN;
    if (u < 51200) {
        int tap = u >> 11; int r = u & 2047; int n = r >> 6; int k = r & 63;
        wb0[u] = (k < 52) ? f2bf(w0[n * 1300 + k * 25 + tap]) : (unsigned short)0;
    } else if (u < 76800) {
        int v = u - 51200; int tap = v >> 10; int r = v & 1023; int n = r >> 5; int k = r & 31;
        wb1[v] = f2bf(w1[n * 800 + k * 25 + tap]);
    } else if (u < 89600) {
        int v = u - 76800; int tap = v >> 9; int r = v & 511; int n = r >> 5; int k = r & 31;
        wb2[v] = (n < 2) ? f2bf(w2[n * 800 + k * 25 + tap]) : (unsigned short)0;
    }
}

// ---------- K1: fused normalize, 16-lane groups (4 pixels/wave) ----------
// blocks 0..4095: vis -> kn ; blocks 4096..8191: rubin bilinear -> qn
__global__ __launch_bounds__(256) void norm_fused(const float* __restrict__ vis,
                                                  const float* __restrict__ rub,
                                                  unsigned short* __restrict__ kn,
                                                  unsigned short* __restrict__ qn) {
    int tid = threadIdx.x;
    int g16 = tid >> 4, l = tid & 15;
    int blk = blockIdx.x;
    if (blk < 4096) {
        int pix = blk * 16 + g16;
        const float* base = vis + (size_t)pix * Dd + l * 4;
        float4 v[4];
#pragma unroll
        for (int i = 0; i < 4; i++) v[i] = *(const float4*)(base + i * 64);
        float ss = 0.f;
#pragma unroll
        for (int i = 0; i < 4; i++)
            ss += v[i].x * v[i].x + v[i].y * v[i].y + v[i].z * v[i].z + v[i].w * v[i].w;
#pragma unroll
        for (int o = 1; o <= 8; o <<= 1) ss += __shfl_xor(ss, o, 64);
        float inv = __builtin_amdgcn_rsqf(fmaxf(ss, 1e-24f));
        unsigned short* op = kn + (size_t)pix * Dd + l * 4;
#pragma unroll
        for (int i = 0; i < 4; i++) {
            ushort4 o4;
            o4.x = f2bf(v[i].x * inv); o4.y = f2bf(v[i].y * inv);
            o4.z = f2bf(v[i].z * inv); o4.w = f2bf(v[i].w * inv);
            *(ushort4*)(op + i * 64) = o4;
        }
    } else {
        int pix = (blk - 4096) * 16 + g16;
        int b = pix >> 14; int yx = pix & 16383; int y = yx >> 7; int x = yx & 127;
        float sy = 0.5f * y - 0.25f;
        float sx = 0.5f * x - 0.25f;
        int y0 = (int)floorf(sy); float fy = sy - (float)y0;
        int x0 = (int)floorf(sx); float fx = sx - (float)x0;
        int y0c = max(y0, 0), y1c = min(y0 + 1, 63);
        int x0c = max(x0, 0), x1c = min(x0 + 1, 63);
        const float* base = rub + (size_t)b * 4096 * Dd + l * 4;
        const float* p00 = base + (size_t)(y0c * 64 + x0c) * Dd;
        const float* p01 = base + (size_t)(y0c * 64 + x1c) * Dd;
        const float* p10 = base + (size_t)(y1c * 64 + x0c) * Dd;
        const float* p11 = base + (size_t)(y1c * 64 + x1c) * Dd;
        float w00 = (1.f - fy) * (1.f - fx), w01 = (1.f - fy) * fx;
        float w10 = fy * (1.f - fx), w11 = fy * fx;
        float4 bv[4];
        float ss = 0.f;
#pragma unroll
        for (int i = 0; i < 4; i++) {
            float4 a = *(const float4*)(p00 + i * 64);
            float4 b1 = *(const float4*)(p01 + i * 64);
            float4 c = *(const float4*)(p10 + i * 64);
            float4 d = *(const float4*)(p11 + i * 64);
            float4 v;
            v.x = w00 * a.x + w01 * b1.x + w10 * c.x + w11 * d.x;
            v.y = w00 * a.y + w01 * b1.y + w10 * c.y + w11 * d.y;
            v.z = w00 * a.z + w01 * b1.z + w10 * c.z + w11 * d.z;
            v.w = w00 * a.w + w01 * b1.w + w10 * c.w + w11 * d.w;
            bv[i] = v;
            ss += v.x * v.x + v.y * v.y + v.z * v.z + v.w * v.w;
        }
#pragma unroll
        for (int o = 1; o <= 8; o <<= 1) ss += __shfl_xor(ss, o, 64);
        float inv = __builtin_amdgcn_rsqf(fmaxf(ss, 1e-24f));
        unsigned short* op = qn + (size_t)pix * Dd + l * 4;
#pragma unroll
        for (int i = 0; i < 4; i++) {
            ushort4 o4;
            o4.x = f2bf(bv[i].x * inv); o4.y = f2bf(bv[i].y * inv);
            o4.z = f2bf(bv[i].z * inv); o4.w = f2bf(bv[i].w * inv);
            *(ushort4*)(op + i * 64) = o4;
        }
    }
}

// ---------- K2: 2D-tiled LDS corr + shuffle softmax (unchanged from R6) ----------
__global__ __launch_bounds__(1024) void corr_block(const unsigned short* __restrict__ qn,
                                                   const unsigned short* __restrict__ kn,
                                                   const float* __restrict__ log_temp,
                                                   unsigned short* __restrict__ xb,
                                                   float* __restrict__ out) {
    __shared__ char smem[484 * 5 * 16];
    int tid = threadIdx.x;
    int wid = tid >> 6, lane = tid & 63, l15 = lane & 15, quad = lane >> 4;
    int blk = blockIdx.x;
    int b = blk >> 6, rem = blk & 63;
    int y0 = ((rem >> 3) & 7) << 4, x0 = (rem & 7) << 4;
    int y = y0 + wid;

    const unsigned short* src0; int dst0;
    const unsigned short* src1 = nullptr; int dst1 = 0;
    bool hav1;
    {
        int g = tid;
        int px = g >> 2, sub = g & 3;
        int ry = px / 22, rx = px - ry * 22;
        int yy = min(max(y0 - 3 + ry, 0), 127);
        int xx = min(max(x0 - 3 + rx, 0), 127);
        src0 = kn + ((size_t)(b << 14) + yy * 128 + xx) * 256 + sub * 8;
        dst0 = (px * 5 + sub) * 16;
        g = 1024 + tid;
        hav1 = (g < 1936);
        int gc = hav1 ? g : 1935;
        px = gc >> 2; sub = gc & 3;
        ry = px / 22; rx = px - ry * 22;
        yy = min(max(y0 - 3 + ry, 0), 127);
        xx = min(max(x0 - 3 + rx, 0), 127);
        src1 = kn + ((size_t)(b << 14) + yy * 128 + xx) * 256 + sub * 8;
        dst1 = (px * 5 + sub) * 16;
    }
    int lpixoff[10];
#pragma unroll
    for (int f = 0; f < 10; f++) {
        int p = min(f * 16 + l15, 153);
        int pr = p / 22, pc = p - pr * 22;
        lpixoff[f] = (((wid + pr) * 22 + pc) * 5 + quad) * 16;
    }
    const unsigned short* aptr = qn + ((size_t)(b << 14) + y * 128 + x0 + l15) * 256 + quad * 8;

    f32x4 acc[10];
#pragma unroll
    for (int f = 0; f < 10; f++) acc[f] = (f32x4){0.f, 0.f, 0.f, 0.f};

    uint4 v0 = *(const uint4*)src0;
    uint4 v1 = *(const uint4*)src1;
    s16x8 an = *(const s16x8*)aptr;
    for (int c = 0; c < 8; c++) {
        uint4 w0v = v0, w1v = v1;
        s16x8 a = an;
        if (c < 7) {
            v0 = *(const uint4*)(src0 + (c + 1) * 32);
            v1 = *(const uint4*)(src1 + (c + 1) * 32);
            an = *(const s16x8*)(aptr + (c + 1) * 32);
        }
        __syncthreads();
        *(uint4*)(smem + dst0) = w0v;
        if (hav1) *(uint4*)(smem + dst1) = w1v;
        __syncthreads();
#pragma unroll
        for (int f = 0; f < 10; f++) {
            s16x8 bf = *(const s16x8*)(smem + lpixoff[f]);
            acc[f] = __builtin_amdgcn_mfma_f32_16x16x32_bf16(a, bf, acc[f], 0, 0, 0);
        }
    }

    float inv_temp = expf(-log_temp[0]);
    float vmax[4] = {-1e30f, -1e30f, -1e30f, -1e30f};
#pragma unroll
    for (int f = 0; f < 10; f++) {
        int n = f * 16 + l15;
        if (n <= 153) {
            int dy = n / 22 - 3;
            int rx = n - (dy + 3) * 22;
#pragma unroll
            for (int i = 0; i < 4; i++) {
                int m = quad * 4 + i;
                int dx = rx - m - 3;
                if ((unsigned)(dx + 3) <= 6u) vmax[i] = fmaxf(vmax[i], acc[f][i]);
            }
        }
    }
#pragma unroll
    for (int o = 1; o <= 8; o <<= 1) {
#pragma unroll
        for (int i = 0; i < 4; i++) vmax[i] = fmaxf(vmax[i], __shfl_xor(vmax[i], o, 64));
    }
    float se[4] = {0, 0, 0, 0}, sey[4] = {0, 0, 0, 0}, sex[4] = {0, 0, 0, 0}, emax[4] = {0, 0, 0, 0};
    unsigned short* xrow = xb + ((size_t)(b * WP + y + 2) * WP + x0 + 2) * 64;
#pragma unroll
    for (int f = 0; f < 10; f++) {
        int n = f * 16 + l15;
        if (n <= 153) {
            int dy = n / 22 - 3;
            int rx = n - (dy + 3) * 22;
#pragma unroll
            for (int i = 0; i < 4; i++) {
                int m = quad * 4 + i;
                int dx = rx - m - 3;
                if ((unsigned)(dx + 3) <= 6u) {
                    float v = acc[f][i];
                    float e = expf((v - vmax[i]) * inv_temp);
                    se[i] += e;
                    sey[i] += e * (float)dy;
                    sex[i] += e * (float)dx;
                    emax[i] = fmaxf(emax[i], e);
                    xrow[(size_t)m * 64 + 2 + (dy + 3) * 7 + (dx + 3)] = f2bf(v);
                }
            }
        }
    }
#pragma unroll
    for (int o = 1; o <= 8; o <<= 1) {
#pragma unroll
        for (int i = 0; i < 4; i++) {
            se[i] += __shfl_xor(se[i], o, 64);
            sey[i] += __shfl_xor(sey[i], o, 64);
            sex[i] += __shfl_xor(sex[i], o, 64);
            emax[i] = fmaxf(emax[i], __shfl_xor(emax[i], o, 64));
        }
    }
    if (l15 == 0) {
#pragma unroll
        for (int i = 0; i < 4; i++) {
            int m = quad * 4 + i;
            float inv_se = 1.0f / se[i];
            float dyv = sey[i] * inv_se, dxv = sex[i] * inv_se, conf = emax[i] * inv_se;
            unsigned short* xp = xrow + (size_t)m * 64;
            xp[0] = f2bf(dyv); xp[1] = f2bf(dxv); xp[51] = f2bf(conf);
            float* op = out + (size_t)b * 5 * HW + y * 128 + x0 + m;
            op[2 * HW] = dyv; op[3 * HW] = dxv; op[4 * HW] = conf;
        }
    }
}

// ---------- 16x16-tile MFMA conv: block=1024thr/16 waves, wave = 16px row x OC ----------
// A halo 20x20 staged per 32-ch K-chunk (ASTR=5 granules/px -> 2-way conflicts only)
template <int KS, int OC, bool GELU>
__global__ __launch_bounds__(1024) void conv_tile(const unsigned short* __restrict__ in,
                                                  const unsigned short* __restrict__ wb,
                                                  const float* __restrict__ bias,
                                                  unsigned short* __restrict__ outp) {
    constexpr int ICP = KS * 32;
    constexpr int NF = OC / 16;
    constexpr int ABYTES = 400 * 5 * 16;        // 32000
    constexpr int WBYTES = 5 * OC * 5 * 16;     // OC*400
    __shared__ char smem[ABYTES + WBYTES];
    int tid = threadIdx.x;
    int wv = tid >> 6, lane = tid & 63, l15 = lane & 15, quad = lane >> 4;
    int blk = blockIdx.x;
    int b = blk >> 6, ty = (blk >> 3) & 7, tx = blk & 7;
    int y0 = ty * 16, x0 = tx * 16;

    f32x4 acc[NF];
#pragma unroll
    for (int g = 0; g < NF; g++) acc[g] = (f32x4){0.f, 0.f, 0.f, 0.f};

    for (int ks = 0; ks < KS; ks++) {
        __syncthreads();           // prior chunk's compute done
        // stage A chunk: 400 px x 4 granules (1600 granules, 2 rounds)
#pragma unroll
        for (int i = 0; i < 2; i++) {
            int g = i * 1024 + tid;
            if (g < 1600) {
                int px = g >> 2, sub = g & 3;
                int r = px / 20, c = px - r * 20;
                *(uint4*)(smem + (px * 5 + sub) * 16) =
                    *(const uint4*)(in + ((size_t)(b * WP + y0 + r) * WP + x0 + c) * ICP + ks * 32 + sub * 8);
            }
        }
        for (int ky = 0; ky < 5; ky++) {
            if (ky > 0) __syncthreads();    // prior compute done (W region free)
            // stage W chunk: taps ky*5..ky*5+4, this ks slice: 5*OC*4 granules
            constexpr int WGR = 5 * OC * 4;
#pragma unroll
            for (int i = 0; i < (WGR + 1023) / 1024; i++) {
                int g = i * 1024 + tid;
                if (g < WGR) {
                    int nl = g >> 2, sub = g & 3;
                    *(uint4*)(smem + ABYTES + (nl * 5 + sub) * 16) =
                        *(const uint4*)(wb + ((size_t)(ky * 5 * OC) + nl) * ICP + ks * 32 + sub * 8);
                }
            }
            __syncthreads();
#pragma unroll
            for (int kx = 0; kx < 5; kx++) {
                int abyte = (((wv + ky) * 20 + l15 + kx) * 5 + quad) * 16;
                s16x8 a = *(const s16x8*)(smem + abyte);
#pragma unroll
                for (int g = 0; g < NF; g++) {
                    int wbyte = ABYTES + ((kx * OC + g * 16 + l15) * 5 + quad) * 16;
                    s16x8 bf = *(const s16x8*)(smem + wbyte);
                    acc[g] = __builtin_amdgcn_mfma_f32_16x16x32_bf16(a, bf, acc[g], 0, 0, 0);
                }
            }
        }
    }
    // epilogue: wave wv -> output row y0+wv; px m = quad*4+r; oc n = g*16+l15
    size_t orow = ((size_t)(b * WP + y0 + wv + 2) * WP + x0 + 2) * OC;
#pragma unroll
    for (int g = 0; g < NF; g++) {
        float bv = bias[g * 16 + l15];
#pragma unroll
        for (int r = 0; r < 4; r++) {
            int m = quad * 4 + r;
            float v = acc[g][r] + bv;
            if (GELU) v = gelu_exact(v);
            outp[orow + (size_t)m * OC + g * 16 + l15] = f2bf(v);
        }
    }
}

// ---------- final conv (32->2, OC padded 16), tile version + residual + sky scaling ----------
__global__ __launch_bounds__(1024) void conv_final_tile(const unsigned short* __restrict__ in,
                                                        const unsigned short* __restrict__ wb,
                                                        const float* __restrict__ bias,
                                                        float* __restrict__ out) {
    constexpr int ICP = 32, OC = 16;
    constexpr int ABYTES = 400 * 5 * 16;
    constexpr int WBYTES = 5 * OC * 5 * 16;   // 6400
    __shared__ char smem[ABYTES + WBYTES];
    int tid = threadIdx.x;
    int wv = tid >> 6, lane = tid & 63, l15 = lane & 15, quad = lane >> 4;
    int blk = blockIdx.x;
    int b = blk >> 6, ty = (blk >> 3) & 7, tx = blk & 7;
    int y0 = ty * 16, x0 = tx * 16;

    f32x4 acc = (f32x4){0.f, 0.f, 0.f, 0.f};
    __syncthreads();
#pragma unroll
    for (int i = 0; i < 2; i++) {
        int g = i * 1024 + tid;
        if (g < 1600) {
            int px = g >> 2, sub = g & 3;
            int r = px / 20, c = px - r * 20;
            *(uint4*)(smem + (px * 5 + sub) * 16) =
                *(const uint4*)(in + ((size_t)(b * WP + y0 + r) * WP + x0 + c) * ICP + sub * 8);
        }
    }
    for (int ky = 0; ky < 5; ky++) {
        if (ky > 0) __syncthreads();
        constexpr int WGR = 5 * OC * 4;   // 320
        {
            int g = tid;
            if (g < WGR) {
                int nl = g >> 2, sub = g & 3;
                *(uint4*)(smem + ABYTES + (nl * 5 + sub) * 16) =
                    *(const uint4*)(wb + ((size_t)(ky * 5 * OC) + nl) * ICP + sub * 8);
            }
        }
        __syncthreads();
#pragma unroll
        for (int kx = 0; kx < 5; kx++) {
            int abyte = (((wv + ky) * 20 + l15 + kx) * 5 + quad) * 16;
            s16x8 a = *(const s16x8*)(smem + abyte);
            int wbyte = ABYTES + ((kx * OC + l15) * 5 + quad) * 16;
            s16x8 bf = *(const s16x8*)(smem + wbyte);
            acc = __builtin_amdgcn_mfma_f32_16x16x32_bf16(a, bf, acc, 0, 0, 0);
        }
    }
    if (l15 < 2) {
        float bv = bias[l15];
#pragma unroll
        for (int r = 0; r < 4; r++) {
            int m = quad * 4 + r;
            size_t p5 = (size_t)b * 5 * HW + (y0 + wv) * Ww + x0 + m;
            float a = acc[r] + bv;
            if (l15 == 0) {
                float dyv = out[p5 + 2 * HW];
                out[p5 + HW] = (dyv + a) * 1.6f;   // ddec
            } else {
                float dxv = out[p5 + 3 * HW];
                out[p5] = (dxv + a) * 1.6f;        // dra
            }
        }
    }
}

extern "C" void kernel_launch(void* const* d_in, const int* in_sizes, int n_in,
                              void* d_out, int out_size, void* d_ws, size_t ws_size,
                              hipStream_t stream) {
    const float* rub = (const float*)d_in[0];
    const float* vis = (const float*)d_in[1];
    const float* w0 = (const float*)d_in[2];
    const float* b0 = (const float*)d_in[3];
    const float* w1 = (const float*)d_in[4];
    const float* b1 = (const float*)d_in[5];
    const float* w2 = (const float*)d_in[6];
    const float* b2 = (const float*)d_in[7];
    const float* log_temp = (const float*)d_in[8];
    float* out = (float*)d_out;

    char* ws = (char*)d_ws;
    size_t off = 0;
    const size_t PADPIX = (size_t)Bb * WP * WP;     // 69,696
    unsigned short* kn = (unsigned short*)(ws + off); off += (size_t)NPIX * Dd * 2;
    unsigned short* qn = (unsigned short*)(ws + off); off += (size_t)NPIX * Dd * 2;
    unsigned short* xbp = (unsigned short*)(ws + off); off += PADPIX * 64 * 2;   // contiguous
    unsigned short* h1p = (unsigned short*)(ws + off); off += PADPIX * 32 * 2;   //  zero
    unsigned short* h2p = (unsigned short*)(ws + off); off += PADPIX * 32 * 2;   //  region
    unsigned short* wb0 = (unsigned short*)(ws + off); off += 51200 * 2;
    unsigned short* wb1 = (unsigned short*)(ws + off); off += 25600 * 2;
    unsigned short* wb2 = (unsigned short*)(ws + off); off += 12800 * 2;

    setup_fill<<<4706, 256, 0, stream>>>(w0, w1, w2, wb0, wb1, wb2, (uint4*)xbp);
    norm_fused<<<8192, 256, 0, stream>>>(vis, rub, kn, qn);
    corr_block<<<256, 1024, 0, stream>>>(qn, kn, log_temp, xbp, out);
    conv_tile<2, 32, true><<<256, 1024, 0, stream>>>(xbp, wb0, b0, h1p);
    conv_tile<1, 32, true><<<256, 1024, 0, stream>>>(h1p, wb1, b1, h2p);
    conv_final_tile<<<256, 1024, 0, stream>>>(h2p, wb2, b2, out);
}